// Round 13
// baseline (281.963 us; speedup 1.0000x reference)
//
#include <hip/hip_runtime.h>
#include <hip/hip_bf16.h>
#include <stdint.h>

#define B_ 2
#define N_ 2048
#define D_ 1024
#define H_ 16
#define MM 4096
#define NN 1024
#define KK 1024

typedef __bf16 bf16;
typedef __bf16 bf16x8 __attribute__((ext_vector_type(8)));
typedef float f32x4 __attribute__((ext_vector_type(4)));

struct __align__(8) bf4 { bf16 v[4]; };

#define LDS_STRIDE 144   // 64 bf16 + 8 pad (Q/K rows)
#define PSTR 272         // 128 bf16 + 8 pad (P/V rows)
#define LOG2E 1.44269504088896340736f

// ---------------------------------------------------------------- weights^T
__global__ void k_wtt4(const float* __restrict__ Wq, const float* __restrict__ Wk,
                       const float* __restrict__ Wv, const float* __restrict__ Wo,
                       bf16* __restrict__ WqT, bf16* __restrict__ WkT,
                       bf16* __restrict__ WvT, bf16* __restrict__ WoT) {
    const int z = blockIdx.z;
    const float* W = z == 0 ? Wq : z == 1 ? Wk : z == 2 ? Wv : Wo;
    bf16* Wt = z == 0 ? WqT : z == 1 ? WkT : z == 2 ? WvT : WoT;
    __shared__ float t[32][33];
    int bx = blockIdx.x * 32, by = blockIdx.y * 32;
    int tx = threadIdx.x, ty = threadIdx.y;
#pragma unroll
    for (int j = 0; j < 32; j += 8)
        t[ty + j][tx] = W[(size_t)(by + ty + j) * 1024 + bx + tx];
    __syncthreads();
#pragma unroll
    for (int j = 0; j < 32; j += 8)
        Wt[(size_t)(bx + ty + j) * 1024 + by + tx] = (bf16)t[tx][ty + j];
}

// ---------------------------------------------------------------- mask bits
__global__ __launch_bounds__(256) void k_bits(const int* __restrict__ mask,
                                              uint32_t* __restrict__ bits) {
    size_t flat = (size_t)blockIdx.x * 256 + threadIdx.x;
    int col = (int)(flat & (N_ - 1));
    int row = (int)((flat >> 11) & (N_ - 1));
    bool ok = (mask[flat] != 0) && (col <= row);
    unsigned long long bal = __ballot(ok);
    if ((threadIdx.x & 63) == 0)
        *(unsigned long long*)(bits + (flat >> 5)) = bal;
}

// ---------------------------------------------------------------- GEMM (kernel-B)
template <int MODE, bool AF32>
__global__ __launch_bounds__(256) void k_gemm(const void* __restrict__ Av,
                                              const bf16* __restrict__ Bt,
                                              bf16* __restrict__ Cb,
                                              float* __restrict__ Cf,
                                              const float* __restrict__ resid,
                                              float scale) {
    __shared__ __align__(16) char AsB[64 * LDS_STRIDE];
    __shared__ __align__(16) char BsB[128 * LDS_STRIDE];
    const int tid = threadIdx.x, lane = tid & 63, w = tid >> 6;
    const int g = lane >> 4, li = lane & 15;
    const int bm0 = blockIdx.x * 64, bn0 = blockIdx.y * 128;
    const int srow = tid >> 3, sc = tid & 7;
    const bf16* Ab = (const bf16*)Av;
    const float* Af = (const float*)Av;

    f32x4 zz = {0.f, 0.f, 0.f, 0.f};
    f32x4 acc[4][2];
#pragma unroll
    for (int mf = 0; mf < 4; ++mf)
#pragma unroll
        for (int nf = 0; nf < 2; ++nf) acc[mf][nf] = zz;

    f32x4 pa0[2], pa1[2];
    bf16x8 pab[2];
    bf16x8 pb[4];

    auto issueA = [&](int k0) {
        if constexpr (AF32) {
#pragma unroll
            for (int i = 0; i < 2; ++i) {
                const float* s = Af + (size_t)(bm0 + srow + 32 * i) * KK + k0 + sc * 8;
                pa0[i] = *(const f32x4*)s;
                pa1[i] = *(const f32x4*)(s + 4);
            }
        } else {
#pragma unroll
            for (int i = 0; i < 2; ++i)
                pab[i] = *(const bf16x8*)(Ab + (size_t)(bm0 + srow + 32 * i) * KK + k0 + sc * 8);
        }
    };
    auto issueB = [&](int k0) {
#pragma unroll
        for (int i = 0; i < 4; ++i)
            pb[i] = *(const bf16x8*)(Bt + (size_t)(bn0 + srow + 32 * i) * KK + k0 + sc * 8);
    };
    auto writeS = [&]() {
#pragma unroll
        for (int i = 0; i < 2; ++i) {
            bf16x8 t;
            if constexpr (AF32) {
#pragma unroll
                for (int j = 0; j < 4; ++j) {
                    t[j] = (bf16)pa0[i][j];
                    t[4 + j] = (bf16)pa1[i][j];
                }
            } else {
                t = pab[i];
            }
            *(bf16x8*)(AsB + (srow + 32 * i) * LDS_STRIDE + sc * 16) = t;
        }
#pragma unroll
        for (int i = 0; i < 4; ++i)
            *(bf16x8*)(BsB + (srow + 32 * i) * LDS_STRIDE + sc * 16) = pb[i];
    };

    issueA(0);
    issueB(0);
    for (int k0 = 0; k0 < KK; k0 += 64) {
        __syncthreads();
        writeS();
        int kn = (k0 + 64 < KK) ? k0 + 64 : k0;
        issueA(kn);
        issueB(kn);
        __syncthreads();
#pragma unroll
        for (int kk = 0; kk < 2; ++kk) {
            const int kb = kk * 64 + (g << 4);
            bf16x8 bfr[2];
#pragma unroll
            for (int nf = 0; nf < 2; ++nf) {
                int rn = w * 32 + nf * 16 + li;
                bfr[nf] = *(const bf16x8*)(BsB + rn * LDS_STRIDE + kb);
            }
#pragma unroll
            for (int mf = 0; mf < 4; ++mf) {
                int rm = mf * 16 + li;
                bf16x8 afr = *(const bf16x8*)(AsB + rm * LDS_STRIDE + kb);
                acc[mf][0] = __builtin_amdgcn_mfma_f32_16x16x32_bf16(
                    afr, bfr[0], acc[mf][0], 0, 0, 0);
                acc[mf][1] = __builtin_amdgcn_mfma_f32_16x16x32_bf16(
                    afr, bfr[1], acc[mf][1], 0, 0, 0);
            }
        }
    }
#pragma unroll
    for (int mf = 0; mf < 4; ++mf)
#pragma unroll
        for (int nf = 0; nf < 2; ++nf) {
            int n = bn0 + w * 32 + nf * 16 + li;
            int m0 = bm0 + mf * 16 + (g << 2);
            if (MODE == 0) {
#pragma unroll
                for (int r = 0; r < 4; ++r)
                    Cb[(size_t)(m0 + r) * NN + n] = (bf16)(acc[mf][nf][r] * scale);
            } else if (MODE == 1) {
                int bq = m0 >> 11, tok = m0 & (N_ - 1);
                int hh = n >> 6, dv = n & 63;
                bf4 val;
#pragma unroll
                for (int r = 0; r < 4; ++r) val.v[r] = (bf16)(acc[mf][nf][r] * scale);
                *(bf4*)(Cb + ((size_t)((bq * H_ + hh) * 64 + dv)) * N_ + tok) = val;
            } else {
#pragma unroll
                for (int r = 0; r < 4; ++r) {
                    size_t ix = (size_t)(m0 + r) * NN + n;
                    Cf[ix] = acc[mf][nf][r] + resid[ix];
                }
            }
        }
}

// ---------------------------------------------------------------- attention
// R8 structure; pass A upgraded to 256-row K staging by aliasing the Vs/Ps
// region (pass A uses only Qs+K): pass-A rounds 17 -> 9 per block (flat for
// every pair p). Pass B unchanged (KVBLK=128, full Ps). LDS total 62464 B.
__global__ __launch_bounds__(256) void k_attn(const bf16* __restrict__ Qh,
                                              const bf16* __restrict__ Kh,
                                              const bf16* __restrict__ Vt,
                                              const uint32_t* __restrict__ bits,
                                              float* __restrict__ attnp,
                                              bf16* __restrict__ Ob) {
    __shared__ __align__(16) char Qs[64 * LDS_STRIDE];   //  9216
    __shared__ __align__(16) char KVP[53248];            // Ks | Vs | Ps union
    char* Ks = KVP;                  // pass B: 128 x 144 = 18432
    char* Vs = KVP + 18432;          // pass B: 64 x 272  = 17408
    char* Ps = KVP + 35840;          // pass B: 64 x 272  = 17408
    char* K256 = KVP;                // pass A: 256 x 144 = 36864 (aliases Ks+Vs+part of Ps)

    const int tid = threadIdx.x, lane = tid & 63, w = tid >> 6;
    const int g = lane >> 4, li = lane & 15;
    const int p = blockIdx.x, h = blockIdx.y, b = blockIdx.z;
    const int srow = tid >> 3, sc = tid & 7;   // srow 0..31, sc 0..7
    const int myrow = w * 16 + li;

    const size_t kbase = ((size_t)b * N_) * D_ + h * 64;
    const size_t vbase = ((size_t)(b * H_ + h) * 64) * N_;
    f32x4 zz = {0.f, 0.f, 0.f, 0.f};

    bf16x8 kr[4], vr[4], kr8[8];
    auto loadK = [&](int jt) {  // 128-row K tile (pass B)
#pragma unroll
        for (int i = 0; i < 4; ++i)
            kr[i] = *(const bf16x8*)(Kh + kbase +
                (size_t)(jt * 128 + srow + 32 * i) * D_ + sc * 8);
    };
    auto writeK = [&]() {
#pragma unroll
        for (int i = 0; i < 4; ++i)
            *(bf16x8*)(Ks + (srow + 32 * i) * LDS_STRIDE + sc * 16) = kr[i];
    };
    auto loadK256 = [&](int jt) {  // 256-row K tile (pass A)
#pragma unroll
        for (int i = 0; i < 8; ++i)
            kr8[i] = *(const bf16x8*)(Kh + kbase +
                (size_t)(jt * 256 + srow + 32 * i) * D_ + sc * 8);
    };
    auto writeK256 = [&]() {
#pragma unroll
        for (int i = 0; i < 8; ++i)
            *(bf16x8*)(K256 + (srow + 32 * i) * LDS_STRIDE + sc * 16) = kr8[i];
    };
    auto loadV = [&](int jt) {  // V tile: 64 dv-rows x 128 tok-cols
#pragma unroll
        for (int c = 0; c < 4; ++c) {
            int row = srow + 32 * (c & 1);
            int cc = sc + 8 * (c >> 1);
            vr[c] = *(const bf16x8*)(Vt + vbase + (size_t)row * N_ + jt * 128 + cc * 8);
        }
    };
    auto writeV = [&]() {
#pragma unroll
        for (int c = 0; c < 4; ++c) {
            int row = srow + 32 * (c & 1);
            int cc = sc + 8 * (c >> 1);
            *(bf16x8*)(Vs + row * PSTR + cc * 16) = vr[c];
        }
    };

    for (int half = 0; half < 2; ++half) {
        const int qt = half ? (31 - p) : p;
        const int i0 = qt << 6;
        const int R = (qt + 2) >> 1;    // 128-col rounds (pass B)
        const int R2 = (qt + 4) >> 2;   // 256-col rounds (pass A); sums to 9/pair
        const size_t abase = (((size_t)b * H_ + h) * N_ + i0) * (size_t)N_;

        __syncthreads();  // previous half's LDS reads done
        {  // stage Q (64 rows x 64 cols)
            const bf16* qsrc = Qh + kbase + (size_t)(i0 + srow) * D_ + sc * 8;
            bf16x8 t0 = *(const bf16x8*)qsrc;
            bf16x8 t1 = *(const bf16x8*)(qsrc + (size_t)32 * D_);
            *(bf16x8*)(Qs + srow * LDS_STRIDE + sc * 16) = t0;
            *(bf16x8*)(Qs + (srow + 32) * LDS_STRIDE + sc * 16) = t1;
        }
        const uint32_t* mrow = bits + (((size_t)b * N_ + i0 + myrow) << 6);

        // ================= pass A: row stats (256-row K tiles) =================
        float m = -1e30f, l = 0.f;
        loadK256(0);
        for (int jt = 0; jt < R2; ++jt) {
            __syncthreads();
            writeK256();
            loadK256((jt + 1 < R2) ? jt + 1 : jt);
            uint4 mw0 = *(const uint4*)(mrow + (jt << 3));
            uint4 mw1 = *(const uint4*)(mrow + (jt << 3) + 4);
            __syncthreads();

#pragma unroll
            for (int sub = 0; sub < 2; ++sub) {
                const uint4 mw = sub ? mw1 : mw0;
                f32x4 s[8];
#pragma unroll
                for (int mf = 0; mf < 8; ++mf) s[mf] = zz;
#pragma unroll
                for (int kk = 0; kk < 2; ++kk) {
                    const int kb = kk * 64 + (g << 4);
                    bf16x8 qf = *(const bf16x8*)(Qs + myrow * LDS_STRIDE + kb);
#pragma unroll
                    for (int mf = 0; mf < 8; ++mf) {
                        bf16x8 kf = *(const bf16x8*)(K256 +
                            (sub * 128 + mf * 16 + li) * LDS_STRIDE + kb);
                        s[mf] = __builtin_amdgcn_mfma_f32_16x16x32_bf16(kf, qf, s[mf], 0, 0, 0);
                    }
                }
                float tmax = m;
#pragma unroll
                for (int mf = 0; mf < 8; ++mf) {
                    uint32_t wsel = (mf < 2) ? mw.x : (mf < 4) ? mw.y : (mf < 6) ? mw.z : mw.w;
#pragma unroll
                    for (int r = 0; r < 4; ++r) {
                        int sh = (mf & 1) * 16 + g * 4 + r;
                        float xv = ((wsel >> sh) & 1) ? s[mf][r] : -1e9f;
                        s[mf][r] = xv;
                        tmax = fmaxf(tmax, xv);
                    }
                }
                tmax = fmaxf(tmax, __shfl_xor(tmax, 16));
                tmax = fmaxf(tmax, __shfl_xor(tmax, 32));
                float ps = 0.f;
#pragma unroll
                for (int mf = 0; mf < 8; ++mf)
#pragma unroll
                    for (int r = 0; r < 4; ++r) ps += exp2f(s[mf][r] - tmax);
                ps += __shfl_xor(ps, 16);
                ps += __shfl_xor(ps, 32);
                l = l * exp2f(m - tmax) + ps;
                m = tmax;
            }
        }
        const float ml = m + __log2f(l);   // P = exp2(x - ml)

        // ================= pass B: P + O (128-col rounds) =================
        f32x4 oacc[4];
#pragma unroll
        for (int nf = 0; nf < 4; ++nf) oacc[nf] = zz;

        loadK(0);
        loadV(0);
        for (int jt = 0; jt < R; ++jt) {
            __syncthreads();
            writeK();
            writeV();
            {
                int jn = (jt + 1 < R) ? jt + 1 : jt;
                loadK(jn);
                loadV(jn);
            }
            uint4 mw = *(const uint4*)(mrow + (jt << 2));
            __syncthreads();

            f32x4 s[8];
#pragma unroll
            for (int mf = 0; mf < 8; ++mf) s[mf] = zz;
#pragma unroll
            for (int kk = 0; kk < 2; ++kk) {
                const int kb = kk * 64 + (g << 4);
                bf16x8 qf = *(const bf16x8*)(Qs + myrow * LDS_STRIDE + kb);
#pragma unroll
                for (int mf = 0; mf < 8; ++mf) {
                    bf16x8 kf = *(const bf16x8*)(Ks + (mf * 16 + li) * LDS_STRIDE + kb);
                    s[mf] = __builtin_amdgcn_mfma_f32_16x16x32_bf16(kf, qf, s[mf], 0, 0, 0);
                }
            }

#pragma unroll
            for (int mf = 0; mf < 8; ++mf) {
                uint32_t wsel = (mf < 2) ? mw.x : (mf < 4) ? mw.y : (mf < 6) ? mw.z : mw.w;
#pragma unroll
                for (int r = 0; r < 4; ++r) {
                    int sh = (mf & 1) * 16 + g * 4 + r;
                    float xv = ((wsel >> sh) & 1) ? s[mf][r] : -1e9f;
                    s[mf][r] = exp2f(xv - ml);
                }
                *(f32x4*)(attnp + abase + (size_t)myrow * N_ + (jt << 7) + mf * 16 + g * 4) = s[mf];
                bf4 pk;
#pragma unroll
                for (int r = 0; r < 4; ++r) pk.v[r] = (bf16)s[mf][r];
                *(bf4*)(Ps + myrow * PSTR + (mf * 16 + g * 4) * 2) = pk;
            }
            // PV over k=128 (Ps rows written/read by same wave)
#pragma unroll
            for (int kk = 0; kk < 4; ++kk) {
                const int kb = kk * 64 + (g << 4);
                bf16x8 pf = *(const bf16x8*)(Ps + myrow * PSTR + kb);
#pragma unroll
                for (int nf = 0; nf < 4; ++nf) {
                    bf16x8 vf = *(const bf16x8*)(Vs + (nf * 16 + li) * PSTR + kb);
                    oacc[nf] = __builtin_amdgcn_mfma_f32_16x16x32_bf16(pf, vf, oacc[nf], 0, 0, 0);
                }
            }
        }
        // O store
#pragma unroll
        for (int nf = 0; nf < 4; ++nf)
#pragma unroll
            for (int r = 0; r < 4; ++r) {
                int gi = i0 + w * 16 + g * 4 + r;
                Ob[((size_t)(b * N_ + gi)) * D_ + h * 64 + nf * 16 + li] = (bf16)oacc[nf][r];
            }
        // zero-fill cols [R*128, N)
        int zc0 = R << 7;
        if (zc0 < N_) {
            int r = tid >> 2, tc = tid & 3;
            f32x4 z = zz;
            for (int c = zc0 + tc * 4; c < N_; c += 16)
                *(f32x4*)(attnp + abase + (size_t)r * N_ + c) = z;
        }
    }
}

// ---------------------------------------------------------------- layernorm
__global__ __launch_bounds__(256) void k_ln(float* __restrict__ out,
                                            const float* __restrict__ gamma,
                                            const float* __restrict__ beta) {
    const int row = blockIdx.x, t = threadIdx.x, lane = t & 63, w = t >> 6;
    float* p = out + (size_t)row * D_;
    f32x4 x = *(const f32x4*)(p + t * 4);
    float s = x[0] + x[1] + x[2] + x[3];
    float s2 = x[0] * x[0] + x[1] * x[1] + x[2] * x[2] + x[3] * x[3];
#pragma unroll
    for (int o = 1; o < 64; o <<= 1) {
        s += __shfl_xor(s, o);
        s2 += __shfl_xor(s2, o);
    }
    __shared__ float r1[4], r2[4];
    if (lane == 0) { r1[w] = s; r2[w] = s2; }
    __syncthreads();
    s = r1[0] + r1[1] + r1[2] + r1[3];
    s2 = r2[0] + r2[1] + r2[2] + r2[3];
    float mean = s * (1.f / D_);
    float var = s2 * (1.f / D_) - mean * mean;
    float rstd = rsqrtf(var + 1e-6f);
    f32x4 gv = *(const f32x4*)(gamma + t * 4);
    f32x4 bv = *(const f32x4*)(beta + t * 4);
    f32x4 y;
#pragma unroll
    for (int c = 0; c < 4; ++c) y[c] = (x[c] - mean) * rstd * gv[c] + bv[c];
    *(f32x4*)(p + t * 4) = y;
}

// ---------------------------------------------------------------- launch
extern "C" void kernel_launch(void* const* d_in, const int* in_sizes, int n_in,
                              void* d_out, int out_size, void* d_ws,
                              size_t ws_size, hipStream_t stream) {
    (void)in_sizes; (void)n_in; (void)out_size; (void)ws_size;
    const float* q = (const float*)d_in[0];
    const float* k = (const float*)d_in[1];
    const float* v = (const float*)d_in[2];
    const int* msk = (const int*)d_in[3];
    const float* Wq = (const float*)d_in[4];
    const float* Wk = (const float*)d_in[5];
    const float* Wv = (const float*)d_in[6];
    const float* Wo = (const float*)d_in[7];
    const float* gamma = (const float*)d_in[8];
    const float* beta = (const float*)d_in[9];

    float* outp = (float*)d_out;
    float* attnp = outp + (size_t)B_ * N_ * D_;

    const size_t U = (size_t)B_ * N_ * D_;
    const size_t W1 = (size_t)D_ * D_;
    bf16* ws = (bf16*)d_ws;
    bf16* WqT = ws;  ws += W1;
    bf16* WkT = ws;  ws += W1;
    bf16* WvT = ws;  ws += W1;
    bf16* WoT = ws;  ws += W1;
    bf16* Qh = ws;   ws += U;
    bf16* Kh = ws;   ws += U;
    bf16* Vt = ws;   ws += U;   // (B,H,DV,N)
    bf16* Ob = ws;   ws += U;
    uint32_t* bits = (uint32_t*)ws;  // 1 MB

    k_wtt4<<<dim3(32, 32, 4), dim3(32, 8), 0, stream>>>(Wq, Wk, Wv, Wo, WqT, WkT, WvT, WoT);
    k_bits<<<(size_t)B_ * N_ * N_ / 256, 256, 0, stream>>>(msk, bits);

    dim3 gg(MM / 64, NN / 128);
    k_gemm<0, true><<<gg, 256, 0, stream>>>(q, WqT, Qh, nullptr, nullptr, 0.125f * LOG2E);
    k_gemm<0, true><<<gg, 256, 0, stream>>>(k, WkT, Kh, nullptr, nullptr, 1.0f);
    k_gemm<1, true><<<gg, 256, 0, stream>>>(v, WvT, Vt, nullptr, nullptr, 1.0f);

    k_attn<<<dim3(16, H_, B_), 256, 0, stream>>>(Qh, Kh, Vt, bits, attnp, Ob);

    k_gemm<2, false><<<gg, 256, 0, stream>>>(Ob, WoT, nullptr, outp, q, 1.0f);

    k_ln<<<B_ * N_, 256, 0, stream>>>(outp, gamma, beta);
}

// Round 14
// 278.838 us; speedup vs baseline: 1.0112x; 1.0112x over previous
//
#include <hip/hip_runtime.h>
#include <hip/hip_bf16.h>
#include <stdint.h>

#define B_ 2
#define N_ 2048
#define D_ 1024
#define H_ 16
#define MM 4096
#define NN 1024
#define KK 1024

typedef __bf16 bf16;
typedef __bf16 bf16x8 __attribute__((ext_vector_type(8)));
typedef float f32x4 __attribute__((ext_vector_type(4)));

struct __align__(8) bf4 { bf16 v[4]; };

#define LDS_STRIDE 144   // 64 bf16 + 8 pad (Q/K rows)
#define PSTR 272         // 128 bf16 + 8 pad (P/V rows), 16B-aligned, 4-bank stagger
#define LOG2E 1.44269504088896340736f

// ---------------------------------------------------------------- weights^T
__global__ void k_wtt4(const float* __restrict__ Wq, const float* __restrict__ Wk,
                       const float* __restrict__ Wv, const float* __restrict__ Wo,
                       bf16* __restrict__ WqT, bf16* __restrict__ WkT,
                       bf16* __restrict__ WvT, bf16* __restrict__ WoT) {
    const int z = blockIdx.z;
    const float* W = z == 0 ? Wq : z == 1 ? Wk : z == 2 ? Wv : Wo;
    bf16* Wt = z == 0 ? WqT : z == 1 ? WkT : z == 2 ? WvT : WoT;
    __shared__ float t[32][33];
    int bx = blockIdx.x * 32, by = blockIdx.y * 32;
    int tx = threadIdx.x, ty = threadIdx.y;
#pragma unroll
    for (int j = 0; j < 32; j += 8)
        t[ty + j][tx] = W[(size_t)(by + ty + j) * 1024 + bx + tx];
    __syncthreads();
#pragma unroll
    for (int j = 0; j < 32; j += 8)
        Wt[(size_t)(bx + ty + j) * 1024 + by + tx] = (bf16)t[tx][ty + j];
}

// ---------------------------------------------------------------- mask bits
// bits[b][row][w]: bit j = (mask != 0) && (col <= row)   (causal folded)
__global__ __launch_bounds__(256) void k_bits(const int* __restrict__ mask,
                                              uint32_t* __restrict__ bits) {
    size_t flat = (size_t)blockIdx.x * 256 + threadIdx.x;
    int col = (int)(flat & (N_ - 1));
    int row = (int)((flat >> 11) & (N_ - 1));
    bool ok = (mask[flat] != 0) && (col <= row);
    unsigned long long bal = __ballot(ok);
    if ((threadIdx.x & 63) == 0)
        *(unsigned long long*)(bits + (flat >> 5)) = bal;
}

// ---------------------------------------------------------------- GEMM (kernel-B)
// C = A @ Bt^T; A: MMxKK (f32 converted in-flight, or bf16), Bt: NNxKK bf16.
// 64x128 tile, BK=64, 4 waves. MODE 0: Cb bf16 (scaled); MODE 1: Vt[b][h][dv][tok];
// MODE 2: Cf = acc + resid
template <int MODE, bool AF32>
__global__ __launch_bounds__(256) void k_gemm(const void* __restrict__ Av,
                                              const bf16* __restrict__ Bt,
                                              bf16* __restrict__ Cb,
                                              float* __restrict__ Cf,
                                              const float* __restrict__ resid,
                                              float scale) {
    __shared__ __align__(16) char AsB[64 * LDS_STRIDE];
    __shared__ __align__(16) char BsB[128 * LDS_STRIDE];
    const int tid = threadIdx.x, lane = tid & 63, w = tid >> 6;
    const int g = lane >> 4, li = lane & 15;
    const int bm0 = blockIdx.x * 64, bn0 = blockIdx.y * 128;
    const int srow = tid >> 3, sc = tid & 7;
    const bf16* Ab = (const bf16*)Av;
    const float* Af = (const float*)Av;

    f32x4 zz = {0.f, 0.f, 0.f, 0.f};
    f32x4 acc[4][2];
#pragma unroll
    for (int mf = 0; mf < 4; ++mf)
#pragma unroll
        for (int nf = 0; nf < 2; ++nf) acc[mf][nf] = zz;

    f32x4 pa0[2], pa1[2];
    bf16x8 pab[2];
    bf16x8 pb[4];

    auto issueA = [&](int k0) {
        if constexpr (AF32) {
#pragma unroll
            for (int i = 0; i < 2; ++i) {
                const float* s = Af + (size_t)(bm0 + srow + 32 * i) * KK + k0 + sc * 8;
                pa0[i] = *(const f32x4*)s;
                pa1[i] = *(const f32x4*)(s + 4);
            }
        } else {
#pragma unroll
            for (int i = 0; i < 2; ++i)
                pab[i] = *(const bf16x8*)(Ab + (size_t)(bm0 + srow + 32 * i) * KK + k0 + sc * 8);
        }
    };
    auto issueB = [&](int k0) {
#pragma unroll
        for (int i = 0; i < 4; ++i)
            pb[i] = *(const bf16x8*)(Bt + (size_t)(bn0 + srow + 32 * i) * KK + k0 + sc * 8);
    };
    auto writeS = [&]() {
#pragma unroll
        for (int i = 0; i < 2; ++i) {
            bf16x8 t;
            if constexpr (AF32) {
#pragma unroll
                for (int j = 0; j < 4; ++j) {
                    t[j] = (bf16)pa0[i][j];
                    t[4 + j] = (bf16)pa1[i][j];
                }
            } else {
                t = pab[i];
            }
            *(bf16x8*)(AsB + (srow + 32 * i) * LDS_STRIDE + sc * 16) = t;
        }
#pragma unroll
        for (int i = 0; i < 4; ++i)
            *(bf16x8*)(BsB + (srow + 32 * i) * LDS_STRIDE + sc * 16) = pb[i];
    };

    issueA(0);
    issueB(0);
    for (int k0 = 0; k0 < KK; k0 += 64) {
        __syncthreads();
        writeS();
        int kn = (k0 + 64 < KK) ? k0 + 64 : k0;
        issueA(kn);
        issueB(kn);
        __syncthreads();
#pragma unroll
        for (int kk = 0; kk < 2; ++kk) {
            const int kb = kk * 64 + (g << 4);
            bf16x8 bfr[2];
#pragma unroll
            for (int nf = 0; nf < 2; ++nf) {
                int rn = w * 32 + nf * 16 + li;
                bfr[nf] = *(const bf16x8*)(BsB + rn * LDS_STRIDE + kb);
            }
#pragma unroll
            for (int mf = 0; mf < 4; ++mf) {
                int rm = mf * 16 + li;
                bf16x8 afr = *(const bf16x8*)(AsB + rm * LDS_STRIDE + kb);
                acc[mf][0] = __builtin_amdgcn_mfma_f32_16x16x32_bf16(
                    afr, bfr[0], acc[mf][0], 0, 0, 0);
                acc[mf][1] = __builtin_amdgcn_mfma_f32_16x16x32_bf16(
                    afr, bfr[1], acc[mf][1], 0, 0, 0);
            }
        }
    }
#pragma unroll
    for (int mf = 0; mf < 4; ++mf)
#pragma unroll
        for (int nf = 0; nf < 2; ++nf) {
            int n = bn0 + w * 32 + nf * 16 + li;
            int m0 = bm0 + mf * 16 + (g << 2);
            if (MODE == 0) {
#pragma unroll
                for (int r = 0; r < 4; ++r)
                    Cb[(size_t)(m0 + r) * NN + n] = (bf16)(acc[mf][nf][r] * scale);
            } else if (MODE == 1) {
                int bq = m0 >> 11, tok = m0 & (N_ - 1);
                int hh = n >> 6, dv = n & 63;
                bf4 val;
#pragma unroll
                for (int r = 0; r < 4; ++r) val.v[r] = (bf16)(acc[mf][nf][r] * scale);
                *(bf4*)(Cb + ((size_t)((bq * H_ + hh) * 64 + dv)) * N_ + tok) = val;
            } else {
#pragma unroll
                for (int r = 0; r < 4; ++r) {
                    size_t ix = (size_t)(m0 + r) * NN + n;
                    Cf[ix] = acc[mf][nf][r] + resid[ix];
                }
            }
        }
}

// ---------------------------------------------------------------- attention
// Kernel-B structure, KVBLK=128: block = (pair p, h, b); qt = p and 31-p.
// Rounds per pass per half = ceil((qt+1)/2); sum over halves = 17 exactly for
// every p -> perfectly flat, dispatch-independent. Swapped QK^T; single-buffer
// K/V (2 barriers/round); reg prefetch; exp2-domain softmax (scale pre-folded).
__global__ __launch_bounds__(256) void k_attn(const bf16* __restrict__ Qh,
                                              const bf16* __restrict__ Kh,
                                              const bf16* __restrict__ Vt,
                                              const uint32_t* __restrict__ bits,
                                              float* __restrict__ attnp,
                                              bf16* __restrict__ Ob) {
    __shared__ __align__(16) char Qs[64 * LDS_STRIDE];    //  9216
    __shared__ __align__(16) char Ks[128 * LDS_STRIDE];   // 18432
    __shared__ __align__(16) char Vs[64 * PSTR];          // 17408 (rows=dv, cols=128 tok)
    __shared__ __align__(16) char Ps[64 * PSTR];          // 17408 (rows=q, cols=128 tok)
    const int tid = threadIdx.x, lane = tid & 63, w = tid >> 6;
    const int g = lane >> 4, li = lane & 15;
    const int p = blockIdx.x, h = blockIdx.y, b = blockIdx.z;
    const int srow = tid >> 3, sc = tid & 7;   // srow 0..31, sc 0..7
    const int myrow = w * 16 + li;

    const size_t kbase = ((size_t)b * N_) * D_ + h * 64;
    const size_t vbase = ((size_t)(b * H_ + h) * 64) * N_;
    f32x4 zz = {0.f, 0.f, 0.f, 0.f};

    bf16x8 kr[4], vr[4];
    auto loadK = [&](int jt) {  // K tile: 128 rows x 64 cols
#pragma unroll
        for (int i = 0; i < 4; ++i)
            kr[i] = *(const bf16x8*)(Kh + kbase +
                (size_t)(jt * 128 + srow + 32 * i) * D_ + sc * 8);
    };
    auto writeK = [&]() {
#pragma unroll
        for (int i = 0; i < 4; ++i)
            *(bf16x8*)(Ks + (srow + 32 * i) * LDS_STRIDE + sc * 16) = kr[i];
    };
    auto loadV = [&](int jt) {  // V tile: 64 dv-rows x 128 tok-cols
#pragma unroll
        for (int c = 0; c < 4; ++c) {
            int row = srow + 32 * (c & 1);
            int cc = sc + 8 * (c >> 1);
            vr[c] = *(const bf16x8*)(Vt + vbase + (size_t)row * N_ + jt * 128 + cc * 8);
        }
    };
    auto writeV = [&]() {
#pragma unroll
        for (int c = 0; c < 4; ++c) {
            int row = srow + 32 * (c & 1);
            int cc = sc + 8 * (c >> 1);
            *(bf16x8*)(Vs + row * PSTR + cc * 16) = vr[c];
        }
    };

    for (int half = 0; half < 2; ++half) {
        const int qt = half ? (31 - p) : p;
        const int i0 = qt << 6;
        const int R = (qt + 2) >> 1;   // 128-col rounds
        const size_t abase = (((size_t)b * H_ + h) * N_ + i0) * (size_t)N_;

        __syncthreads();  // previous half's LDS reads done
        {  // stage Q (64 rows x 64 cols)
            const bf16* qsrc = Qh + kbase + (size_t)(i0 + srow) * D_ + sc * 8;
            bf16x8 t0 = *(const bf16x8*)qsrc;
            bf16x8 t1 = *(const bf16x8*)(qsrc + (size_t)32 * D_);
            *(bf16x8*)(Qs + srow * LDS_STRIDE + sc * 16) = t0;
            *(bf16x8*)(Qs + (srow + 32) * LDS_STRIDE + sc * 16) = t1;
        }
        const uint32_t* mrow = bits + (((size_t)b * N_ + i0 + myrow) << 6);

        // ================= pass A: row stats =================
        float m = -1e30f, l = 0.f;
        loadK(0);
        for (int jt = 0; jt < R; ++jt) {
            __syncthreads();
            writeK();
            loadK((jt + 1 < R) ? jt + 1 : jt);
            uint4 mw = *(const uint4*)(mrow + (jt << 2));
            __syncthreads();

            f32x4 s[8];
#pragma unroll
            for (int mf = 0; mf < 8; ++mf) s[mf] = zz;
#pragma unroll
            for (int kk = 0; kk < 2; ++kk) {
                const int kb = kk * 64 + (g << 4);
                bf16x8 qf = *(const bf16x8*)(Qs + myrow * LDS_STRIDE + kb);
#pragma unroll
                for (int mf = 0; mf < 8; ++mf) {
                    bf16x8 kf = *(const bf16x8*)(Ks + (mf * 16 + li) * LDS_STRIDE + kb);
                    s[mf] = __builtin_amdgcn_mfma_f32_16x16x32_bf16(kf, qf, s[mf], 0, 0, 0);
                }
            }
            float tmax = m;
#pragma unroll
            for (int mf = 0; mf < 8; ++mf) {
                uint32_t wsel = (mf < 2) ? mw.x : (mf < 4) ? mw.y : (mf < 6) ? mw.z : mw.w;
#pragma unroll
                for (int r = 0; r < 4; ++r) {
                    int sh = (mf & 1) * 16 + g * 4 + r;
                    float xv = ((wsel >> sh) & 1) ? s[mf][r] : -1e9f;
                    s[mf][r] = xv;
                    tmax = fmaxf(tmax, xv);
                }
            }
            tmax = fmaxf(tmax, __shfl_xor(tmax, 16));
            tmax = fmaxf(tmax, __shfl_xor(tmax, 32));
            float ps = 0.f;
#pragma unroll
            for (int mf = 0; mf < 8; ++mf)
#pragma unroll
                for (int r = 0; r < 4; ++r) ps += exp2f(s[mf][r] - tmax);
            ps += __shfl_xor(ps, 16);
            ps += __shfl_xor(ps, 32);
            l = l * exp2f(m - tmax) + ps;
            m = tmax;
        }
        const float ml = m + __log2f(l);   // P = exp2(x - ml)

        // ================= pass B: P + O =================
        f32x4 oacc[4];
#pragma unroll
        for (int nf = 0; nf < 4; ++nf) oacc[nf] = zz;

        loadK(0);
        loadV(0);
        for (int jt = 0; jt < R; ++jt) {
            __syncthreads();
            writeK();
            writeV();
            {
                int jn = (jt + 1 < R) ? jt + 1 : jt;
                loadK(jn);
                loadV(jn);
            }
            uint4 mw = *(const uint4*)(mrow + (jt << 2));
            __syncthreads();

            f32x4 s[8];
#pragma unroll
            for (int mf = 0; mf < 8; ++mf) s[mf] = zz;
#pragma unroll
            for (int kk = 0; kk < 2; ++kk) {
                const int kb = kk * 64 + (g << 4);
                bf16x8 qf = *(const bf16x8*)(Qs + myrow * LDS_STRIDE + kb);
#pragma unroll
                for (int mf = 0; mf < 8; ++mf) {
                    bf16x8 kf = *(const bf16x8*)(Ks + (mf * 16 + li) * LDS_STRIDE + kb);
                    s[mf] = __builtin_amdgcn_mfma_f32_16x16x32_bf16(kf, qf, s[mf], 0, 0, 0);
                }
            }

#pragma unroll
            for (int mf = 0; mf < 8; ++mf) {
                uint32_t wsel = (mf < 2) ? mw.x : (mf < 4) ? mw.y : (mf < 6) ? mw.z : mw.w;
#pragma unroll
                for (int r = 0; r < 4; ++r) {
                    int sh = (mf & 1) * 16 + g * 4 + r;
                    float xv = ((wsel >> sh) & 1) ? s[mf][r] : -1e9f;
                    s[mf][r] = exp2f(xv - ml);
                }
                *(f32x4*)(attnp + abase + (size_t)myrow * N_ + (jt << 7) + mf * 16 + g * 4) = s[mf];
                bf4 pk;
#pragma unroll
                for (int r = 0; r < 4; ++r) pk.v[r] = (bf16)s[mf][r];
                *(bf4*)(Ps + myrow * PSTR + (mf * 16 + g * 4) * 2) = pk;
            }
            // PV over k=128 (Ps rows written/read by same wave)
#pragma unroll
            for (int kk = 0; kk < 4; ++kk) {
                const int kb = kk * 64 + (g << 4);
                bf16x8 pf = *(const bf16x8*)(Ps + myrow * PSTR + kb);
#pragma unroll
                for (int nf = 0; nf < 4; ++nf) {
                    bf16x8 vf = *(const bf16x8*)(Vs + (nf * 16 + li) * PSTR + kb);
                    oacc[nf] = __builtin_amdgcn_mfma_f32_16x16x32_bf16(pf, vf, oacc[nf], 0, 0, 0);
                }
            }
        }
        // O store
#pragma unroll
        for (int nf = 0; nf < 4; ++nf)
#pragma unroll
            for (int r = 0; r < 4; ++r) {
                int gi = i0 + w * 16 + g * 4 + r;
                Ob[((size_t)(b * N_ + gi)) * D_ + h * 64 + nf * 16 + li] = (bf16)oacc[nf][r];
            }
        // zero-fill cols [R*128, N)
        int zc0 = R << 7;
        if (zc0 < N_) {
            int r = tid >> 2, tc = tid & 3;
            f32x4 z = zz;
            for (int c = zc0 + tc * 4; c < N_; c += 16)
                *(f32x4*)(attnp + abase + (size_t)r * N_ + c) = z;
        }
    }
}

// ---------------------------------------------------------------- layernorm
__global__ __launch_bounds__(256) void k_ln(float* __restrict__ out,
                                            const float* __restrict__ gamma,
                                            const float* __restrict__ beta) {
    const int row = blockIdx.x, t = threadIdx.x, lane = t & 63, w = t >> 6;
    float* p = out + (size_t)row * D_;
    f32x4 x = *(const f32x4*)(p + t * 4);
    float s = x[0] + x[1] + x[2] + x[3];
    float s2 = x[0] * x[0] + x[1] * x[1] + x[2] * x[2] + x[3] * x[3];
#pragma unroll
    for (int o = 1; o < 64; o <<= 1) {
        s += __shfl_xor(s, o);
        s2 += __shfl_xor(s2, o);
    }
    __shared__ float r1[4], r2[4];
    if (lane == 0) { r1[w] = s; r2[w] = s2; }
    __syncthreads();
    s = r1[0] + r1[1] + r1[2] + r1[3];
    s2 = r2[0] + r2[1] + r2[2] + r2[3];
    float mean = s * (1.f / D_);
    float var = s2 * (1.f / D_) - mean * mean;
    float rstd = rsqrtf(var + 1e-6f);
    f32x4 gv = *(const f32x4*)(gamma + t * 4);
    f32x4 bv = *(const f32x4*)(beta + t * 4);
    f32x4 y;
#pragma unroll
    for (int c = 0; c < 4; ++c) y[c] = (x[c] - mean) * rstd * gv[c] + bv[c];
    *(f32x4*)(p + t * 4) = y;
}

// ---------------------------------------------------------------- launch
extern "C" void kernel_launch(void* const* d_in, const int* in_sizes, int n_in,
                              void* d_out, int out_size, void* d_ws,
                              size_t ws_size, hipStream_t stream) {
    (void)in_sizes; (void)n_in; (void)out_size; (void)ws_size;
    const float* q = (const float*)d_in[0];
    const float* k = (const float*)d_in[1];
    const float* v = (const float*)d_in[2];
    const int* msk = (const int*)d_in[3];
    const float* Wq = (const float*)d_in[4];
    const float* Wk = (const float*)d_in[5];
    const float* Wv = (const float*)d_in[6];
    const float* Wo = (const float*)d_in[7];
    const float* gamma = (const float*)d_in[8];
    const float* beta = (const float*)d_in[9];

    float* outp = (float*)d_out;
    float* attnp = outp + (size_t)B_ * N_ * D_;

    const size_t U = (size_t)B_ * N_ * D_;
    const size_t W1 = (size_t)D_ * D_;
    bf16* ws = (bf16*)d_ws;
    bf16* WqT = ws;  ws += W1;
    bf16* WkT = ws;  ws += W1;
    bf16* WvT = ws;  ws += W1;
    bf16* WoT = ws;  ws += W1;
    bf16* Qh = ws;   ws += U;
    bf16* Kh = ws;   ws += U;
    bf16* Vt = ws;   ws += U;   // (B,H,DV,N)
    bf16* Ob = ws;   ws += U;
    uint32_t* bits = (uint32_t*)ws;  // 1 MB

    k_wtt4<<<dim3(32, 32, 4), dim3(32, 8), 0, stream>>>(Wq, Wk, Wv, Wo, WqT, WkT, WvT, WoT);
    k_bits<<<(size_t)B_ * N_ * N_ / 256, 256, 0, stream>>>(msk, bits);

    dim3 gg(MM / 64, NN / 128);
    k_gemm<0, true><<<gg, 256, 0, stream>>>(q, WqT, Qh, nullptr, nullptr, 0.125f * LOG2E);
    k_gemm<0, true><<<gg, 256, 0, stream>>>(k, WkT, Kh, nullptr, nullptr, 1.0f);
    k_gemm<1, true><<<gg, 256, 0, stream>>>(v, WvT, Vt, nullptr, nullptr, 1.0f);

    k_attn<<<dim3(16, H_, B_), 256, 0, stream>>>(Qh, Kh, Vt, bits, attnp, Ob);

    k_gemm<2, false><<<gg, 256, 0, stream>>>(Ob, WoT, nullptr, outp, q, 1.0f);

    k_ln<<<B_ * N_, 256, 0, stream>>>(outp, gamma, beta);
}

// Round 15
// 268.389 us; speedup vs baseline: 1.0506x; 1.0389x over previous
//
#include <hip/hip_runtime.h>
#include <hip/hip_bf16.h>
#include <stdint.h>

#define B_ 2
#define N_ 2048
#define D_ 1024
#define H_ 16
#define MM 4096
#define NN 1024
#define KK 1024

typedef __bf16 bf16;
typedef __bf16 bf16x8 __attribute__((ext_vector_type(8)));
typedef float f32x4 __attribute__((ext_vector_type(4)));

struct __align__(8) bf4 { bf16 v[4]; };

#define LDS_STRIDE 144   // 64 bf16 + 8 pad (Q/K rows)
#define PSTR 272         // 128 bf16 + 8 pad (P/V rows)
#define LOG2E 1.44269504088896340736f

// ---------------------------------------------------------------- weights^T
__global__ void k_wtt4(const float* __restrict__ Wq, const float* __restrict__ Wk,
                       const float* __restrict__ Wv, const float* __restrict__ Wo,
                       bf16* __restrict__ WqT, bf16* __restrict__ WkT,
                       bf16* __restrict__ WvT, bf16* __restrict__ WoT) {
    const int z = blockIdx.z;
    const float* W = z == 0 ? Wq : z == 1 ? Wk : z == 2 ? Wv : Wo;
    bf16* Wt = z == 0 ? WqT : z == 1 ? WkT : z == 2 ? WvT : WoT;
    __shared__ float t[32][33];
    int bx = blockIdx.x * 32, by = blockIdx.y * 32;
    int tx = threadIdx.x, ty = threadIdx.y;
#pragma unroll
    for (int j = 0; j < 32; j += 8)
        t[ty + j][tx] = W[(size_t)(by + ty + j) * 1024 + bx + tx];
    __syncthreads();
#pragma unroll
    for (int j = 0; j < 32; j += 8)
        Wt[(size_t)(bx + ty + j) * 1024 + by + tx] = (bf16)t[tx][ty + j];
}

// ---------------------------------------------------------------- mask bits
__global__ __launch_bounds__(256) void k_bits(const int* __restrict__ mask,
                                              uint32_t* __restrict__ bits) {
    size_t flat = (size_t)blockIdx.x * 256 + threadIdx.x;
    int col = (int)(flat & (N_ - 1));
    int row = (int)((flat >> 11) & (N_ - 1));
    bool ok = (mask[flat] != 0) && (col <= row);
    unsigned long long bal = __ballot(ok);
    if ((threadIdx.x & 63) == 0)
        *(unsigned long long*)(bits + (flat >> 5)) = bal;
}

// ---------------------------------------------------------------- GEMM core (kernel-B)
// shared body: A (f32 converted in-flight or bf16) @ Bt^T -> acc[4][2]
template <bool AF32>
__device__ __forceinline__ void kb_core(const void* __restrict__ Av,
                                        const bf16* __restrict__ Bt,
                                        int bm0, int bn0,
                                        char* AsB, char* BsB,
                                        f32x4 (&acc)[4][2]) {
    const int tid = threadIdx.x, lane = tid & 63, w = tid >> 6;
    const int g = lane >> 4, li = lane & 15;
    const int srow = tid >> 3, sc = tid & 7;
    const bf16* Ab = (const bf16*)Av;
    const float* Af = (const float*)Av;

    f32x4 zz = {0.f, 0.f, 0.f, 0.f};
#pragma unroll
    for (int mf = 0; mf < 4; ++mf)
#pragma unroll
        for (int nf = 0; nf < 2; ++nf) acc[mf][nf] = zz;

    f32x4 pa0[2], pa1[2];
    bf16x8 pab[2];
    bf16x8 pb[4];

    auto issueA = [&](int k0) {
        if constexpr (AF32) {
#pragma unroll
            for (int i = 0; i < 2; ++i) {
                const float* s = Af + (size_t)(bm0 + srow + 32 * i) * KK + k0 + sc * 8;
                pa0[i] = *(const f32x4*)s;
                pa1[i] = *(const f32x4*)(s + 4);
            }
        } else {
#pragma unroll
            for (int i = 0; i < 2; ++i)
                pab[i] = *(const bf16x8*)(Ab + (size_t)(bm0 + srow + 32 * i) * KK + k0 + sc * 8);
        }
    };
    auto issueB = [&](int k0) {
#pragma unroll
        for (int i = 0; i < 4; ++i)
            pb[i] = *(const bf16x8*)(Bt + (size_t)(bn0 + srow + 32 * i) * KK + k0 + sc * 8);
    };
    auto writeS = [&]() {
#pragma unroll
        for (int i = 0; i < 2; ++i) {
            bf16x8 t;
            if constexpr (AF32) {
#pragma unroll
                for (int j = 0; j < 4; ++j) {
                    t[j] = (bf16)pa0[i][j];
                    t[4 + j] = (bf16)pa1[i][j];
                }
            } else {
                t = pab[i];
            }
            *(bf16x8*)(AsB + (srow + 32 * i) * LDS_STRIDE + sc * 16) = t;
        }
#pragma unroll
        for (int i = 0; i < 4; ++i)
            *(bf16x8*)(BsB + (srow + 32 * i) * LDS_STRIDE + sc * 16) = pb[i];
    };

    issueA(0);
    issueB(0);
    for (int k0 = 0; k0 < KK; k0 += 64) {
        __syncthreads();
        writeS();
        int kn = (k0 + 64 < KK) ? k0 + 64 : k0;
        issueA(kn);
        issueB(kn);
        __syncthreads();
#pragma unroll
        for (int kk = 0; kk < 2; ++kk) {
            const int kb = kk * 64 + (g << 4);
            bf16x8 bfr[2];
#pragma unroll
            for (int nf = 0; nf < 2; ++nf) {
                int rn = w * 32 + nf * 16 + li;
                bfr[nf] = *(const bf16x8*)(BsB + rn * LDS_STRIDE + kb);
            }
#pragma unroll
            for (int mf = 0; mf < 4; ++mf) {
                int rm = mf * 16 + li;
                bf16x8 afr = *(const bf16x8*)(AsB + rm * LDS_STRIDE + kb);
                acc[mf][0] = __builtin_amdgcn_mfma_f32_16x16x32_bf16(
                    afr, bfr[0], acc[mf][0], 0, 0, 0);
                acc[mf][1] = __builtin_amdgcn_mfma_f32_16x16x32_bf16(
                    afr, bfr[1], acc[mf][1], 0, 0, 0);
            }
        }
    }
}

// fused Q/K/V projections: one launch, grid (64, 8, 3); kernel-B internals
__global__ __launch_bounds__(256) void k_proj3(const float* __restrict__ q,
                                               const float* __restrict__ k,
                                               const float* __restrict__ v,
                                               const bf16* __restrict__ WqT,
                                               const bf16* __restrict__ WkT,
                                               const bf16* __restrict__ WvT,
                                               bf16* __restrict__ Qh,
                                               bf16* __restrict__ Kh,
                                               bf16* __restrict__ Vt) {
    __shared__ __align__(16) char AsB[64 * LDS_STRIDE];
    __shared__ __align__(16) char BsB[128 * LDS_STRIDE];
    const int z = blockIdx.z;
    const float* A = z == 0 ? q : z == 1 ? k : v;
    const bf16* Bt = z == 0 ? WqT : z == 1 ? WkT : WvT;
    const float scale = (z == 0) ? 0.125f * LOG2E : 1.0f;
    const int bm0 = blockIdx.x * 64, bn0 = blockIdx.y * 128;

    f32x4 acc[4][2];
    kb_core<true>(A, Bt, bm0, bn0, AsB, BsB, acc);

    const int tid = threadIdx.x, lane = tid & 63, w = tid >> 6;
    const int g = lane >> 4, li = lane & 15;

    if (z < 2) {
        bf16* C = (z == 0) ? Qh : Kh;
#pragma unroll
        for (int mf = 0; mf < 4; ++mf)
#pragma unroll
            for (int nf = 0; nf < 2; ++nf) {
                int n = bn0 + w * 32 + nf * 16 + li;
                int m0 = bm0 + mf * 16 + (g << 2);
#pragma unroll
                for (int r = 0; r < 4; ++r)
                    C[(size_t)(m0 + r) * NN + n] = (bf16)(acc[mf][nf][r] * scale);
            }
    } else {
#pragma unroll
        for (int mf = 0; mf < 4; ++mf)
#pragma unroll
            for (int nf = 0; nf < 2; ++nf) {
                int n = bn0 + w * 32 + nf * 16 + li;
                int m0 = bm0 + mf * 16 + (g << 2);
                int bq = m0 >> 11, tok = m0 & (N_ - 1);
                int hh = n >> 6, dv = n & 63;
                bf4 val;
#pragma unroll
                for (int r = 0; r < 4; ++r) val.v[r] = (bf16)acc[mf][nf][r];
                *(bf4*)(Vt + ((size_t)((bq * H_ + hh) * 64 + dv)) * N_ + tok) = val;
            }
    }
}

// output GEMM: out = Ob @ WoT^T + resid (kernel-B internals)
__global__ __launch_bounds__(256) void k_out(const bf16* __restrict__ Ob,
                                             const bf16* __restrict__ WoT,
                                             float* __restrict__ outp,
                                             const float* __restrict__ resid) {
    __shared__ __align__(16) char AsB[64 * LDS_STRIDE];
    __shared__ __align__(16) char BsB[128 * LDS_STRIDE];
    const int bm0 = blockIdx.x * 64, bn0 = blockIdx.y * 128;

    f32x4 acc[4][2];
    kb_core<false>(Ob, WoT, bm0, bn0, AsB, BsB, acc);

    const int tid = threadIdx.x, lane = tid & 63, w = tid >> 6;
    const int g = lane >> 4, li = lane & 15;
#pragma unroll
    for (int mf = 0; mf < 4; ++mf)
#pragma unroll
        for (int nf = 0; nf < 2; ++nf) {
            int n = bn0 + w * 32 + nf * 16 + li;
            int m0 = bm0 + mf * 16 + (g << 2);
#pragma unroll
            for (int r = 0; r < 4; ++r) {
                size_t ix = (size_t)(m0 + r) * NN + n;
                outp[ix] = acc[mf][nf][r] + resid[ix];
            }
        }
}

// ---------------------------------------------------------------- attention
// R8/R12 verbatim: block = (pair p, h, b); qt = p and 31-p; KVBLK=128.
__global__ __launch_bounds__(256) void k_attn(const bf16* __restrict__ Qh,
                                              const bf16* __restrict__ Kh,
                                              const bf16* __restrict__ Vt,
                                              const uint32_t* __restrict__ bits,
                                              float* __restrict__ attnp,
                                              bf16* __restrict__ Ob) {
    __shared__ __align__(16) char Qs[64 * LDS_STRIDE];    //  9216
    __shared__ __align__(16) char Ks[128 * LDS_STRIDE];   // 18432
    __shared__ __align__(16) char Vs[64 * PSTR];          // 17408
    __shared__ __align__(16) char Ps[64 * PSTR];          // 17408
    const int tid = threadIdx.x, lane = tid & 63, w = tid >> 6;
    const int g = lane >> 4, li = lane & 15;
    const int p = blockIdx.x, h = blockIdx.y, b = blockIdx.z;
    const int srow = tid >> 3, sc = tid & 7;
    const int myrow = w * 16 + li;

    const size_t kbase = ((size_t)b * N_) * D_ + h * 64;
    const size_t vbase = ((size_t)(b * H_ + h) * 64) * N_;
    f32x4 zz = {0.f, 0.f, 0.f, 0.f};

    bf16x8 kr[4], vr[4];
    auto loadK = [&](int jt) {
#pragma unroll
        for (int i = 0; i < 4; ++i)
            kr[i] = *(const bf16x8*)(Kh + kbase +
                (size_t)(jt * 128 + srow + 32 * i) * D_ + sc * 8);
    };
    auto writeK = [&]() {
#pragma unroll
        for (int i = 0; i < 4; ++i)
            *(bf16x8*)(Ks + (srow + 32 * i) * LDS_STRIDE + sc * 16) = kr[i];
    };
    auto loadV = [&](int jt) {
#pragma unroll
        for (int c = 0; c < 4; ++c) {
            int row = srow + 32 * (c & 1);
            int cc = sc + 8 * (c >> 1);
            vr[c] = *(const bf16x8*)(Vt + vbase + (size_t)row * N_ + jt * 128 + cc * 8);
        }
    };
    auto writeV = [&]() {
#pragma unroll
        for (int c = 0; c < 4; ++c) {
            int row = srow + 32 * (c & 1);
            int cc = sc + 8 * (c >> 1);
            *(bf16x8*)(Vs + row * PSTR + cc * 16) = vr[c];
        }
    };

    for (int half = 0; half < 2; ++half) {
        const int qt = half ? (31 - p) : p;
        const int i0 = qt << 6;
        const int R = (qt + 2) >> 1;
        const size_t abase = (((size_t)b * H_ + h) * N_ + i0) * (size_t)N_;

        __syncthreads();
        {
            const bf16* qsrc = Qh + kbase + (size_t)(i0 + srow) * D_ + sc * 8;
            bf16x8 t0 = *(const bf16x8*)qsrc;
            bf16x8 t1 = *(const bf16x8*)(qsrc + (size_t)32 * D_);
            *(bf16x8*)(Qs + srow * LDS_STRIDE + sc * 16) = t0;
            *(bf16x8*)(Qs + (srow + 32) * LDS_STRIDE + sc * 16) = t1;
        }
        const uint32_t* mrow = bits + (((size_t)b * N_ + i0 + myrow) << 6);

        // ================= pass A: row stats =================
        float m = -1e30f, l = 0.f;
        loadK(0);
        for (int jt = 0; jt < R; ++jt) {
            __syncthreads();
            writeK();
            loadK((jt + 1 < R) ? jt + 1 : jt);
            uint4 mw = *(const uint4*)(mrow + (jt << 2));
            __syncthreads();

            f32x4 s[8];
#pragma unroll
            for (int mf = 0; mf < 8; ++mf) s[mf] = zz;
#pragma unroll
            for (int kk = 0; kk < 2; ++kk) {
                const int kb = kk * 64 + (g << 4);
                bf16x8 qf = *(const bf16x8*)(Qs + myrow * LDS_STRIDE + kb);
#pragma unroll
                for (int mf = 0; mf < 8; ++mf) {
                    bf16x8 kf = *(const bf16x8*)(Ks + (mf * 16 + li) * LDS_STRIDE + kb);
                    s[mf] = __builtin_amdgcn_mfma_f32_16x16x32_bf16(kf, qf, s[mf], 0, 0, 0);
                }
            }
            float tmax = m;
#pragma unroll
            for (int mf = 0; mf < 8; ++mf) {
                uint32_t wsel = (mf < 2) ? mw.x : (mf < 4) ? mw.y : (mf < 6) ? mw.z : mw.w;
#pragma unroll
                for (int r = 0; r < 4; ++r) {
                    int sh = (mf & 1) * 16 + g * 4 + r;
                    float xv = ((wsel >> sh) & 1) ? s[mf][r] : -1e9f;
                    s[mf][r] = xv;
                    tmax = fmaxf(tmax, xv);
                }
            }
            tmax = fmaxf(tmax, __shfl_xor(tmax, 16));
            tmax = fmaxf(tmax, __shfl_xor(tmax, 32));
            float ps = 0.f;
#pragma unroll
            for (int mf = 0; mf < 8; ++mf)
#pragma unroll
                for (int r = 0; r < 4; ++r) ps += exp2f(s[mf][r] - tmax);
            ps += __shfl_xor(ps, 16);
            ps += __shfl_xor(ps, 32);
            l = l * exp2f(m - tmax) + ps;
            m = tmax;
        }
        const float ml = m + __log2f(l);

        // ================= pass B: P + O =================
        f32x4 oacc[4];
#pragma unroll
        for (int nf = 0; nf < 4; ++nf) oacc[nf] = zz;

        loadK(0);
        loadV(0);
        for (int jt = 0; jt < R; ++jt) {
            __syncthreads();
            writeK();
            writeV();
            {
                int jn = (jt + 1 < R) ? jt + 1 : jt;
                loadK(jn);
                loadV(jn);
            }
            uint4 mw = *(const uint4*)(mrow + (jt << 2));
            __syncthreads();

            f32x4 s[8];
#pragma unroll
            for (int mf = 0; mf < 8; ++mf) s[mf] = zz;
#pragma unroll
            for (int kk = 0; kk < 2; ++kk) {
                const int kb = kk * 64 + (g << 4);
                bf16x8 qf = *(const bf16x8*)(Qs + myrow * LDS_STRIDE + kb);
#pragma unroll
                for (int mf = 0; mf < 8; ++mf) {
                    bf16x8 kf = *(const bf16x8*)(Ks + (mf * 16 + li) * LDS_STRIDE + kb);
                    s[mf] = __builtin_amdgcn_mfma_f32_16x16x32_bf16(kf, qf, s[mf], 0, 0, 0);
                }
            }

#pragma unroll
            for (int mf = 0; mf < 8; ++mf) {
                uint32_t wsel = (mf < 2) ? mw.x : (mf < 4) ? mw.y : (mf < 6) ? mw.z : mw.w;
#pragma unroll
                for (int r = 0; r < 4; ++r) {
                    int sh = (mf & 1) * 16 + g * 4 + r;
                    float xv = ((wsel >> sh) & 1) ? s[mf][r] : -1e9f;
                    s[mf][r] = exp2f(xv - ml);
                }
                *(f32x4*)(attnp + abase + (size_t)myrow * N_ + (jt << 7) + mf * 16 + g * 4) = s[mf];
                bf4 pk;
#pragma unroll
                for (int r = 0; r < 4; ++r) pk.v[r] = (bf16)s[mf][r];
                *(bf4*)(Ps + myrow * PSTR + (mf * 16 + g * 4) * 2) = pk;
            }
#pragma unroll
            for (int kk = 0; kk < 4; ++kk) {
                const int kb = kk * 64 + (g << 4);
                bf16x8 pf = *(const bf16x8*)(Ps + myrow * PSTR + kb);
#pragma unroll
                for (int nf = 0; nf < 4; ++nf) {
                    bf16x8 vf = *(const bf16x8*)(Vs + (nf * 16 + li) * PSTR + kb);
                    oacc[nf] = __builtin_amdgcn_mfma_f32_16x16x32_bf16(pf, vf, oacc[nf], 0, 0, 0);
                }
            }
        }
#pragma unroll
        for (int nf = 0; nf < 4; ++nf)
#pragma unroll
            for (int r = 0; r < 4; ++r) {
                int gi = i0 + w * 16 + g * 4 + r;
                Ob[((size_t)(b * N_ + gi)) * D_ + h * 64 + nf * 16 + li] = (bf16)oacc[nf][r];
            }
        int zc0 = R << 7;
        if (zc0 < N_) {
            int r = tid >> 2, tc = tid & 3;
            f32x4 z = zz;
            for (int c = zc0 + tc * 4; c < N_; c += 16)
                *(f32x4*)(attnp + abase + (size_t)r * N_ + c) = z;
        }
    }
}

// ---------------------------------------------------------------- layernorm
__global__ __launch_bounds__(256) void k_ln(float* __restrict__ out,
                                            const float* __restrict__ gamma,
                                            const float* __restrict__ beta) {
    const int row = blockIdx.x, t = threadIdx.x, lane = t & 63, w = t >> 6;
    float* p = out + (size_t)row * D_;
    f32x4 x = *(const f32x4*)(p + t * 4);
    float s = x[0] + x[1] + x[2] + x[3];
    float s2 = x[0] * x[0] + x[1] * x[1] + x[2] * x[2] + x[3] * x[3];
#pragma unroll
    for (int o = 1; o < 64; o <<= 1) {
        s += __shfl_xor(s, o);
        s2 += __shfl_xor(s2, o);
    }
    __shared__ float r1[4], r2[4];
    if (lane == 0) { r1[w] = s; r2[w] = s2; }
    __syncthreads();
    s = r1[0] + r1[1] + r1[2] + r1[3];
    s2 = r2[0] + r2[1] + r2[2] + r2[3];
    float mean = s * (1.f / D_);
    float var = s2 * (1.f / D_) - mean * mean;
    float rstd = rsqrtf(var + 1e-6f);
    f32x4 gv = *(const f32x4*)(gamma + t * 4);
    f32x4 bv = *(const f32x4*)(beta + t * 4);
    f32x4 y;
#pragma unroll
    for (int c = 0; c < 4; ++c) y[c] = (x[c] - mean) * rstd * gv[c] + bv[c];
    *(f32x4*)(p + t * 4) = y;
}

// ---------------------------------------------------------------- launch
extern "C" void kernel_launch(void* const* d_in, const int* in_sizes, int n_in,
                              void* d_out, int out_size, void* d_ws,
                              size_t ws_size, hipStream_t stream) {
    (void)in_sizes; (void)n_in; (void)out_size; (void)ws_size;
    const float* q = (const float*)d_in[0];
    const float* k = (const float*)d_in[1];
    const float* v = (const float*)d_in[2];
    const int* msk = (const int*)d_in[3];
    const float* Wq = (const float*)d_in[4];
    const float* Wk = (const float*)d_in[5];
    const float* Wv = (const float*)d_in[6];
    const float* Wo = (const float*)d_in[7];
    const float* gamma = (const float*)d_in[8];
    const float* beta = (const float*)d_in[9];

    float* outp = (float*)d_out;
    float* attnp = outp + (size_t)B_ * N_ * D_;

    const size_t U = (size_t)B_ * N_ * D_;
    const size_t W1 = (size_t)D_ * D_;
    bf16* ws = (bf16*)d_ws;
    bf16* WqT = ws;  ws += W1;
    bf16* WkT = ws;  ws += W1;
    bf16* WvT = ws;  ws += W1;
    bf16* WoT = ws;  ws += W1;
    bf16* Qh = ws;   ws += U;
    bf16* Kh = ws;   ws += U;
    bf16* Vt = ws;   ws += U;   // (B,H,DV,N)
    bf16* Ob = ws;   ws += U;
    uint32_t* bits = (uint32_t*)ws;  // 1 MB

    k_wtt4<<<dim3(32, 32, 4), dim3(32, 8), 0, stream>>>(Wq, Wk, Wv, Wo, WqT, WkT, WvT, WoT);
    k_bits<<<(size_t)B_ * N_ * N_ / 256, 256, 0, stream>>>(msk, bits);

    k_proj3<<<dim3(MM / 64, NN / 128, 3), 256, 0, stream>>>(q, k, v, WqT, WkT, WvT, Qh, Kh, Vt);

    k_attn<<<dim3(16, H_, B_), 256, 0, stream>>>(Qh, Kh, Vt, bits, attnp, Ob);

    k_out<<<dim3(MM / 64, NN / 128), 256, 0, stream>>>(Ob, WoT, outp, q);

    k_ln<<<B_ * N_, 256, 0, stream>>>(outp, gamma, beta);
}

// Round 16
// 259.714 us; speedup vs baseline: 1.0857x; 1.0334x over previous
//
#include <hip/hip_runtime.h>
#include <hip/hip_bf16.h>
#include <stdint.h>

#define B_ 2
#define N_ 2048
#define D_ 1024
#define H_ 16
#define MM 4096
#define NN 1024
#define KK 1024

typedef __bf16 bf16;
typedef __bf16 bf16x8 __attribute__((ext_vector_type(8)));
typedef float f32x4 __attribute__((ext_vector_type(4)));

struct __align__(8) bf4 { bf16 v[4]; };

#define LDS_STRIDE 144   // 64 bf16 + 8 pad (Q/K rows)
#define PSTR 272         // 128 bf16 + 8 pad (P/V rows)
#define LOG2E 1.44269504088896340736f

// ---------------------------------------------------------------- prep (wtt x4 + mask bits, one launch)
__global__ __launch_bounds__(256) void k_prep(const float* __restrict__ Wq,
                                              const float* __restrict__ Wk,
                                              const float* __restrict__ Wv,
                                              const float* __restrict__ Wo,
                                              const int* __restrict__ mask,
                                              bf16* __restrict__ WqT,
                                              bf16* __restrict__ WkT,
                                              bf16* __restrict__ WvT,
                                              bf16* __restrict__ WoT,
                                              uint32_t* __restrict__ bits) {
    __shared__ float tl[32][33];
    const int bid = blockIdx.x;
    if (bid < 4096) {
        // weight transpose: Wt[n][k] = (bf16)W[k][n]
        const int z = bid >> 10, t = bid & 1023;
        const float* W = z == 0 ? Wq : z == 1 ? Wk : z == 2 ? Wv : Wo;
        bf16* Wt = z == 0 ? WqT : z == 1 ? WkT : z == 2 ? WvT : WoT;
        const int bx = (t & 31) * 32, by = (t >> 5) * 32;
        const int tx = threadIdx.x & 31, ty = threadIdx.x >> 5;  // 32 x 8
#pragma unroll
        for (int j = 0; j < 32; j += 8)
            tl[ty + j][tx] = W[(size_t)(by + ty + j) * 1024 + bx + tx];
        __syncthreads();
#pragma unroll
        for (int j = 0; j < 32; j += 8)
            Wt[(size_t)(bx + ty + j) * 1024 + by + tx] = (bf16)tl[tx][ty + j];
    } else {
        // mask bits: bit j = (mask != 0) && (col <= row)
        size_t flat = (size_t)(bid - 4096) * 256 + threadIdx.x;
        int col = (int)(flat & (N_ - 1));
        int row = (int)((flat >> 11) & (N_ - 1));
        bool ok = (mask[flat] != 0) && (col <= row);
        unsigned long long bal = __ballot(ok);
        if ((threadIdx.x & 63) == 0)
            *(unsigned long long*)(bits + (flat >> 5)) = bal;
    }
}

// ---------------------------------------------------------------- GEMM core (kernel-B)
template <bool AF32>
__device__ __forceinline__ void kb_core(const void* __restrict__ Av,
                                        const bf16* __restrict__ Bt,
                                        int bm0, int bn0,
                                        char* AsB, char* BsB,
                                        f32x4 (&acc)[4][2]) {
    const int tid = threadIdx.x, lane = tid & 63, w = tid >> 6;
    const int g = lane >> 4, li = lane & 15;
    const int srow = tid >> 3, sc = tid & 7;
    const bf16* Ab = (const bf16*)Av;
    const float* Af = (const float*)Av;

    f32x4 zz = {0.f, 0.f, 0.f, 0.f};
#pragma unroll
    for (int mf = 0; mf < 4; ++mf)
#pragma unroll
        for (int nf = 0; nf < 2; ++nf) acc[mf][nf] = zz;

    f32x4 pa0[2], pa1[2];
    bf16x8 pab[2];
    bf16x8 pb[4];

    auto issueA = [&](int k0) {
        if constexpr (AF32) {
#pragma unroll
            for (int i = 0; i < 2; ++i) {
                const float* s = Af + (size_t)(bm0 + srow + 32 * i) * KK + k0 + sc * 8;
                pa0[i] = *(const f32x4*)s;
                pa1[i] = *(const f32x4*)(s + 4);
            }
        } else {
#pragma unroll
            for (int i = 0; i < 2; ++i)
                pab[i] = *(const bf16x8*)(Ab + (size_t)(bm0 + srow + 32 * i) * KK + k0 + sc * 8);
        }
    };
    auto issueB = [&](int k0) {
#pragma unroll
        for (int i = 0; i < 4; ++i)
            pb[i] = *(const bf16x8*)(Bt + (size_t)(bn0 + srow + 32 * i) * KK + k0 + sc * 8);
    };
    auto writeS = [&]() {
#pragma unroll
        for (int i = 0; i < 2; ++i) {
            bf16x8 t;
            if constexpr (AF32) {
#pragma unroll
                for (int j = 0; j < 4; ++j) {
                    t[j] = (bf16)pa0[i][j];
                    t[4 + j] = (bf16)pa1[i][j];
                }
            } else {
                t = pab[i];
            }
            *(bf16x8*)(AsB + (srow + 32 * i) * LDS_STRIDE + sc * 16) = t;
        }
#pragma unroll
        for (int i = 0; i < 4; ++i)
            *(bf16x8*)(BsB + (srow + 32 * i) * LDS_STRIDE + sc * 16) = pb[i];
    };

    issueA(0);
    issueB(0);
    for (int k0 = 0; k0 < KK; k0 += 64) {
        __syncthreads();
        writeS();
        int kn = (k0 + 64 < KK) ? k0 + 64 : k0;
        issueA(kn);
        issueB(kn);
        __syncthreads();
#pragma unroll
        for (int kk = 0; kk < 2; ++kk) {
            const int kb = kk * 64 + (g << 4);
            bf16x8 bfr[2];
#pragma unroll
            for (int nf = 0; nf < 2; ++nf) {
                int rn = w * 32 + nf * 16 + li;
                bfr[nf] = *(const bf16x8*)(BsB + rn * LDS_STRIDE + kb);
            }
#pragma unroll
            for (int mf = 0; mf < 4; ++mf) {
                int rm = mf * 16 + li;
                bf16x8 afr = *(const bf16x8*)(AsB + rm * LDS_STRIDE + kb);
                acc[mf][0] = __builtin_amdgcn_mfma_f32_16x16x32_bf16(
                    afr, bfr[0], acc[mf][0], 0, 0, 0);
                acc[mf][1] = __builtin_amdgcn_mfma_f32_16x16x32_bf16(
                    afr, bfr[1], acc[mf][1], 0, 0, 0);
            }
        }
    }
}

// fused Q/K/V projections: one launch, grid (64, 8, 3)
__global__ __launch_bounds__(256) void k_proj3(const float* __restrict__ q,
                                               const float* __restrict__ k,
                                               const float* __restrict__ v,
                                               const bf16* __restrict__ WqT,
                                               const bf16* __restrict__ WkT,
                                               const bf16* __restrict__ WvT,
                                               bf16* __restrict__ Qh,
                                               bf16* __restrict__ Kh,
                                               bf16* __restrict__ Vt) {
    __shared__ __align__(16) char AsB[64 * LDS_STRIDE];
    __shared__ __align__(16) char BsB[128 * LDS_STRIDE];
    const int z = blockIdx.z;
    const float* A = z == 0 ? q : z == 1 ? k : v;
    const bf16* Bt = z == 0 ? WqT : z == 1 ? WkT : WvT;
    const float scale = (z == 0) ? 0.125f * LOG2E : 1.0f;
    const int bm0 = blockIdx.x * 64, bn0 = blockIdx.y * 128;

    f32x4 acc[4][2];
    kb_core<true>(A, Bt, bm0, bn0, AsB, BsB, acc);

    const int tid = threadIdx.x, lane = tid & 63, w = tid >> 6;
    const int g = lane >> 4, li = lane & 15;

    if (z < 2) {
        bf16* C = (z == 0) ? Qh : Kh;
#pragma unroll
        for (int mf = 0; mf < 4; ++mf)
#pragma unroll
            for (int nf = 0; nf < 2; ++nf) {
                int n = bn0 + w * 32 + nf * 16 + li;
                int m0 = bm0 + mf * 16 + (g << 2);
#pragma unroll
                for (int r = 0; r < 4; ++r)
                    C[(size_t)(m0 + r) * NN + n] = (bf16)(acc[mf][nf][r] * scale);
            }
    } else {
#pragma unroll
        for (int mf = 0; mf < 4; ++mf)
#pragma unroll
            for (int nf = 0; nf < 2; ++nf) {
                int n = bn0 + w * 32 + nf * 16 + li;
                int m0 = bm0 + mf * 16 + (g << 2);
                int bq = m0 >> 11, tok = m0 & (N_ - 1);
                int hh = n >> 6, dv = n & 63;
                bf4 val;
#pragma unroll
                for (int r = 0; r < 4; ++r) val.v[r] = (bf16)acc[mf][nf][r];
                *(bf4*)(Vt + ((size_t)((bq * H_ + hh) * 64 + dv)) * N_ + tok) = val;
            }
    }
}

// output GEMM: out = Ob @ WoT^T + resid
__global__ __launch_bounds__(256) void k_out(const bf16* __restrict__ Ob,
                                             const bf16* __restrict__ WoT,
                                             float* __restrict__ outp,
                                             const float* __restrict__ resid) {
    __shared__ __align__(16) char AsB[64 * LDS_STRIDE];
    __shared__ __align__(16) char BsB[128 * LDS_STRIDE];
    const int bm0 = blockIdx.x * 64, bn0 = blockIdx.y * 128;

    f32x4 acc[4][2];
    kb_core<false>(Ob, WoT, bm0, bn0, AsB, BsB, acc);

    const int tid = threadIdx.x, lane = tid & 63, w = tid >> 6;
    const int g = lane >> 4, li = lane & 15;
#pragma unroll
    for (int mf = 0; mf < 4; ++mf)
#pragma unroll
        for (int nf = 0; nf < 2; ++nf) {
            int n = bn0 + w * 32 + nf * 16 + li;
            int m0 = bm0 + mf * 16 + (g << 2);
#pragma unroll
            for (int r = 0; r < 4; ++r) {
                size_t ix = (size_t)(m0 + r) * NN + n;
                outp[ix] = acc[mf][nf][r] + resid[ix];
            }
        }
}

// ---------------------------------------------------------------- attention
// R12/R15 structure verbatim + s_setprio(1) around MFMA clusters (T5: the two
// independent blocks per CU drift out of phase -> scheduler favors MFMA wave).
__global__ __launch_bounds__(256) void k_attn(const bf16* __restrict__ Qh,
                                              const bf16* __restrict__ Kh,
                                              const bf16* __restrict__ Vt,
                                              const uint32_t* __restrict__ bits,
                                              float* __restrict__ attnp,
                                              bf16* __restrict__ Ob) {
    __shared__ __align__(16) char Qs[64 * LDS_STRIDE];    //  9216
    __shared__ __align__(16) char Ks[128 * LDS_STRIDE];   // 18432
    __shared__ __align__(16) char Vs[64 * PSTR];          // 17408
    __shared__ __align__(16) char Ps[64 * PSTR];          // 17408
    const int tid = threadIdx.x, lane = tid & 63, w = tid >> 6;
    const int g = lane >> 4, li = lane & 15;
    const int p = blockIdx.x, h = blockIdx.y, b = blockIdx.z;
    const int srow = tid >> 3, sc = tid & 7;
    const int myrow = w * 16 + li;

    const size_t kbase = ((size_t)b * N_) * D_ + h * 64;
    const size_t vbase = ((size_t)(b * H_ + h) * 64) * N_;
    f32x4 zz = {0.f, 0.f, 0.f, 0.f};

    bf16x8 kr[4], vr[4];
    auto loadK = [&](int jt) {
#pragma unroll
        for (int i = 0; i < 4; ++i)
            kr[i] = *(const bf16x8*)(Kh + kbase +
                (size_t)(jt * 128 + srow + 32 * i) * D_ + sc * 8);
    };
    auto writeK = [&]() {
#pragma unroll
        for (int i = 0; i < 4; ++i)
            *(bf16x8*)(Ks + (srow + 32 * i) * LDS_STRIDE + sc * 16) = kr[i];
    };
    auto loadV = [&](int jt) {
#pragma unroll
        for (int c = 0; c < 4; ++c) {
            int row = srow + 32 * (c & 1);
            int cc = sc + 8 * (c >> 1);
            vr[c] = *(const bf16x8*)(Vt + vbase + (size_t)row * N_ + jt * 128 + cc * 8);
        }
    };
    auto writeV = [&]() {
#pragma unroll
        for (int c = 0; c < 4; ++c) {
            int row = srow + 32 * (c & 1);
            int cc = sc + 8 * (c >> 1);
            *(bf16x8*)(Vs + row * PSTR + cc * 16) = vr[c];
        }
    };

    for (int half = 0; half < 2; ++half) {
        const int qt = half ? (31 - p) : p;
        const int i0 = qt << 6;
        const int R = (qt + 2) >> 1;
        const size_t abase = (((size_t)b * H_ + h) * N_ + i0) * (size_t)N_;

        __syncthreads();
        {
            const bf16* qsrc = Qh + kbase + (size_t)(i0 + srow) * D_ + sc * 8;
            bf16x8 t0 = *(const bf16x8*)qsrc;
            bf16x8 t1 = *(const bf16x8*)(qsrc + (size_t)32 * D_);
            *(bf16x8*)(Qs + srow * LDS_STRIDE + sc * 16) = t0;
            *(bf16x8*)(Qs + (srow + 32) * LDS_STRIDE + sc * 16) = t1;
        }
        const uint32_t* mrow = bits + (((size_t)b * N_ + i0 + myrow) << 6);

        // ================= pass A: row stats =================
        float m = -1e30f, l = 0.f;
        loadK(0);
        for (int jt = 0; jt < R; ++jt) {
            __syncthreads();
            writeK();
            loadK((jt + 1 < R) ? jt + 1 : jt);
            uint4 mw = *(const uint4*)(mrow + (jt << 2));
            __syncthreads();

            f32x4 s[8];
#pragma unroll
            for (int mf = 0; mf < 8; ++mf) s[mf] = zz;
            __builtin_amdgcn_s_setprio(1);
#pragma unroll
            for (int kk = 0; kk < 2; ++kk) {
                const int kb = kk * 64 + (g << 4);
                bf16x8 qf = *(const bf16x8*)(Qs + myrow * LDS_STRIDE + kb);
#pragma unroll
                for (int mf = 0; mf < 8; ++mf) {
                    bf16x8 kf = *(const bf16x8*)(Ks + (mf * 16 + li) * LDS_STRIDE + kb);
                    s[mf] = __builtin_amdgcn_mfma_f32_16x16x32_bf16(kf, qf, s[mf], 0, 0, 0);
                }
            }
            __builtin_amdgcn_s_setprio(0);
            float tmax = m;
#pragma unroll
            for (int mf = 0; mf < 8; ++mf) {
                uint32_t wsel = (mf < 2) ? mw.x : (mf < 4) ? mw.y : (mf < 6) ? mw.z : mw.w;
#pragma unroll
                for (int r = 0; r < 4; ++r) {
                    int sh = (mf & 1) * 16 + g * 4 + r;
                    float xv = ((wsel >> sh) & 1) ? s[mf][r] : -1e9f;
                    s[mf][r] = xv;
                    tmax = fmaxf(tmax, xv);
                }
            }
            tmax = fmaxf(tmax, __shfl_xor(tmax, 16));
            tmax = fmaxf(tmax, __shfl_xor(tmax, 32));
            float ps = 0.f;
#pragma unroll
            for (int mf = 0; mf < 8; ++mf)
#pragma unroll
                for (int r = 0; r < 4; ++r) ps += exp2f(s[mf][r] - tmax);
            ps += __shfl_xor(ps, 16);
            ps += __shfl_xor(ps, 32);
            l = l * exp2f(m - tmax) + ps;
            m = tmax;
        }
        const float ml = m + __log2f(l);

        // ================= pass B: P + O =================
        f32x4 oacc[4];
#pragma unroll
        for (int nf = 0; nf < 4; ++nf) oacc[nf] = zz;

        loadK(0);
        loadV(0);
        for (int jt = 0; jt < R; ++jt) {
            __syncthreads();
            writeK();
            writeV();
            {
                int jn = (jt + 1 < R) ? jt + 1 : jt;
                loadK(jn);
                loadV(jn);
            }
            uint4 mw = *(const uint4*)(mrow + (jt << 2));
            __syncthreads();

            f32x4 s[8];
#pragma unroll
            for (int mf = 0; mf < 8; ++mf) s[mf] = zz;
            __builtin_amdgcn_s_setprio(1);
#pragma unroll
            for (int kk = 0; kk < 2; ++kk) {
                const int kb = kk * 64 + (g << 4);
                bf16x8 qf = *(const bf16x8*)(Qs + myrow * LDS_STRIDE + kb);
#pragma unroll
                for (int mf = 0; mf < 8; ++mf) {
                    bf16x8 kf = *(const bf16x8*)(Ks + (mf * 16 + li) * LDS_STRIDE + kb);
                    s[mf] = __builtin_amdgcn_mfma_f32_16x16x32_bf16(kf, qf, s[mf], 0, 0, 0);
                }
            }
            __builtin_amdgcn_s_setprio(0);

#pragma unroll
            for (int mf = 0; mf < 8; ++mf) {
                uint32_t wsel = (mf < 2) ? mw.x : (mf < 4) ? mw.y : (mf < 6) ? mw.z : mw.w;
#pragma unroll
                for (int r = 0; r < 4; ++r) {
                    int sh = (mf & 1) * 16 + g * 4 + r;
                    float xv = ((wsel >> sh) & 1) ? s[mf][r] : -1e9f;
                    s[mf][r] = exp2f(xv - ml);
                }
                *(f32x4*)(attnp + abase + (size_t)myrow * N_ + (jt << 7) + mf * 16 + g * 4) = s[mf];
                bf4 pk;
#pragma unroll
                for (int r = 0; r < 4; ++r) pk.v[r] = (bf16)s[mf][r];
                *(bf4*)(Ps + myrow * PSTR + (mf * 16 + g * 4) * 2) = pk;
            }
            __builtin_amdgcn_s_setprio(1);
#pragma unroll
            for (int kk = 0; kk < 4; ++kk) {
                const int kb = kk * 64 + (g << 4);
                bf16x8 pf = *(const bf16x8*)(Ps + myrow * PSTR + kb);
#pragma unroll
                for (int nf = 0; nf < 4; ++nf) {
                    bf16x8 vf = *(const bf16x8*)(Vs + (nf * 16 + li) * PSTR + kb);
                    oacc[nf] = __builtin_amdgcn_mfma_f32_16x16x32_bf16(pf, vf, oacc[nf], 0, 0, 0);
                }
            }
            __builtin_amdgcn_s_setprio(0);
        }
#pragma unroll
        for (int nf = 0; nf < 4; ++nf)
#pragma unroll
            for (int r = 0; r < 4; ++r) {
                int gi = i0 + w * 16 + g * 4 + r;
                Ob[((size_t)(b * N_ + gi)) * D_ + h * 64 + nf * 16 + li] = (bf16)oacc[nf][r];
            }
        int zc0 = R << 7;
        if (zc0 < N_) {
            int r = tid >> 2, tc = tid & 3;
            f32x4 z = zz;
            for (int c = zc0 + tc * 4; c < N_; c += 16)
                *(f32x4*)(attnp + abase + (size_t)r * N_ + c) = z;
        }
    }
}

// ---------------------------------------------------------------- layernorm
__global__ __launch_bounds__(256) void k_ln(float* __restrict__ out,
                                            const float* __restrict__ gamma,
                                            const float* __restrict__ beta) {
    const int row = blockIdx.x, t = threadIdx.x, lane = t & 63, w = t >> 6;
    float* p = out + (size_t)row * D_;
    f32x4 x = *(const f32x4*)(p + t * 4);
    float s = x[0] + x[1] + x[2] + x[3];
    float s2 = x[0] * x[0] + x[1] * x[1] + x[2] * x[2] + x[3] * x[3];
#pragma unroll
    for (int o = 1; o < 64; o <<= 1) {
        s += __shfl_xor(s, o);
        s2 += __shfl_xor(s2, o);
    }
    __shared__ float r1[4], r2[4];
    if (lane == 0) { r1[w] = s; r2[w] = s2; }
    __syncthreads();
    s = r1[0] + r1[1] + r1[2] + r1[3];
    s2 = r2[0] + r2[1] + r2[2] + r2[3];
    float mean = s * (1.f / D_);
    float var = s2 * (1.f / D_) - mean * mean;
    float rstd = rsqrtf(var + 1e-6f);
    f32x4 gv = *(const f32x4*)(gamma + t * 4);
    f32x4 bv = *(const f32x4*)(beta + t * 4);
    f32x4 y;
#pragma unroll
    for (int c = 0; c < 4; ++c) y[c] = (x[c] - mean) * rstd * gv[c] + bv[c];
    *(f32x4*)(p + t * 4) = y;
}

// ---------------------------------------------------------------- launch
extern "C" void kernel_launch(void* const* d_in, const int* in_sizes, int n_in,
                              void* d_out, int out_size, void* d_ws,
                              size_t ws_size, hipStream_t stream) {
    (void)in_sizes; (void)n_in; (void)out_size; (void)ws_size;
    const float* q = (const float*)d_in[0];
    const float* k = (const float*)d_in[1];
    const float* v = (const float*)d_in[2];
    const int* msk = (const int*)d_in[3];
    const float* Wq = (const float*)d_in[4];
    const float* Wk = (const float*)d_in[5];
    const float* Wv = (const float*)d_in[6];
    const float* Wo = (const float*)d_in[7];
    const float* gamma = (const float*)d_in[8];
    const float* beta = (const float*)d_in[9];

    float* outp = (float*)d_out;
    float* attnp = outp + (size_t)B_ * N_ * D_;

    const size_t U = (size_t)B_ * N_ * D_;
    const size_t W1 = (size_t)D_ * D_;
    bf16* ws = (bf16*)d_ws;
    bf16* WqT = ws;  ws += W1;
    bf16* WkT = ws;  ws += W1;
    bf16* WvT = ws;  ws += W1;
    bf16* WoT = ws;  ws += W1;
    bf16* Qh = ws;   ws += U;
    bf16* Kh = ws;   ws += U;
    bf16* Vt = ws;   ws += U;   // (B,H,DV,N)
    bf16* Ob = ws;   ws += U;
    uint32_t* bits = (uint32_t*)ws;  // 1 MB

    // 4096 wtt blocks + 16384 bits blocks in one launch
    k_prep<<<4096 + (B_ * N_ * N_ / 256), 256, 0, stream>>>(
        Wq, Wk, Wv, Wo, msk, WqT, WkT, WvT, WoT, bits);

    k_proj3<<<dim3(MM / 64, NN / 128, 3), 256, 0, stream>>>(q, k, v, WqT, WkT, WvT, Qh, Kh, Vt);

    k_attn<<<dim3(16, H_, B_), 256, 0, stream>>>(Qh, Kh, Vt, bits, attnp, Ob);

    k_out<<<dim3(MM / 64, NN / 128), 256, 0, stream>>>(Ob, WoT, outp, q);

    k_ln<<<B_ * N_, 256, 0, stream>>>(outp, gamma, beta);
}